// Round 11
// baseline (78.185 us; speedup 1.0000x reference)
//
#include <hip/hip_runtime.h>

typedef __attribute__((ext_vector_type(8))) short short8;
typedef __attribute__((ext_vector_type(4))) float f32x4;
typedef unsigned int u32;

#define N_IN  4096
#define N_OUT 4096
#define NBAT  256

#define OUT_ACT   0
#define OUT_FICT  1048576
#define OUT_PHYS  2097152
#define OUT_LUT   3145728
#define OUT_TLAST 3211264

// ws layout (~36 MB)
#define WS_AIMG   0                        // 2 MB bf16 mask image, fragment layout
#define WS_BIMG   2097152                  // 33.5 MB bf16 synw image, fragment layout
#define WS_DTF    (WS_BIMG + 33554432)
#define WS_DXA    (WS_DTF + 1024)

__device__ __forceinline__ unsigned f2bf(float f) {
  unsigned u = __float_as_uint(f);
  return (u + 0x7FFFu + ((u >> 16) & 1u)) >> 16;   // RNE to bf16
}

__device__ __forceinline__ void gload16(const void* g, void* l) {
  __builtin_amdgcn_global_load_lds(
      (const __attribute__((address_space(1))) u32*)g,
      (__attribute__((address_space(3))) u32*)l, 16, 0, 0);
}

// ---------------------------------------------------------------------------
// Kernel A: prepass. XOR-parity + delta_t + t_last, AND writes the mask as a
// bf16 image in MFMA-FRAGMENT layout:
//   frag(rg,ktg,kk,mi) at ((rg*64+ktg)*4 + kk*2+mi)*1024 + lane*16
//   holds row b = rg*32+mi*16+(lane&15), k = ktg*64+kk*32+(lane>>4)*8+j
// ---------------------------------------------------------------------------
__global__ __launch_bounds__(256) void snn_pre(
    const int* __restrict__ mask, const int* __restrict__ t_ptr,
    const int* __restrict__ pid, const int* __restrict__ t_last,
    float* __restrict__ dtf_ws, int* __restrict__ dxa_ws,
    char* __restrict__ aimg, float* __restrict__ out)
{
  const int b = blockIdx.x, tid = threadIdx.x;
  const int k0 = tid * 16;
  const int4* mp = (const int4*)(mask + (size_t)b * N_IN + k0);
  const int4* pp = (const int4*)(pid + k0);
  int x = 0;
  u32 wv[8];
#pragma unroll
  for (int q = 0; q < 4; ++q) {
    int4 m = mp[q];
    int4 id = pp[q];
    x ^= (m.x ? id.x : 0) ^ (m.y ? id.y : 0) ^ (m.z ? id.z : 0) ^ (m.w ? id.w : 0);
    wv[q * 2]     = (m.x ? 0x3F80u : 0u) | ((m.y ? 0x3F80u : 0u) << 16);
    wv[q * 2 + 1] = (m.z ? 0x3F80u : 0u) | ((m.w ? 0x3F80u : 0u) << 16);
  }
  {
    const int rg = b >> 5, rl = b & 31;
    const int mi = rl >> 4, l15 = rl & 15;
    const int ktg = tid >> 2, kk = (tid >> 1) & 1, l4_0 = (tid & 1) * 2;
    char* base = aimg + ((size_t)((rg * 64 + ktg) * 4 + kk * 2 + mi) << 10);
    uint4 v0; v0.x = wv[0]; v0.y = wv[1]; v0.z = wv[2]; v0.w = wv[3];
    uint4 v1; v1.x = wv[4]; v1.y = wv[5]; v1.z = wv[6]; v1.w = wv[7];
    *(uint4*)(base + (l4_0 * 16 + l15) * 16)       = v0;
    *(uint4*)(base + ((l4_0 + 1) * 16 + l15) * 16) = v1;
  }
  x ^= __shfl_xor(x, 32); x ^= __shfl_xor(x, 16); x ^= __shfl_xor(x, 8);
  x ^= __shfl_xor(x, 4);  x ^= __shfl_xor(x, 2);  x ^= __shfl_xor(x, 1);
  __shared__ int wx[4];
  if ((tid & 63) == 0) wx[tid >> 6] = x;
  __syncthreads();
  if (tid == 0) {
    int acc = wx[0] ^ wx[1] ^ wx[2] ^ wx[3];
    int tt = t_ptr[0];
    int dt = (tt - t_last[b]) & 15;
    dtf_ws[b] = (float)dt;
    dxa_ws[b] = dt ^ (acc & 15);
    out[OUT_TLAST + b] = (float)tt;
  }
}

// ---------------------------------------------------------------------------
// Kernel W: convert synw (fp32 [k][o]) -> bf16 B-fragment image.
// block = 16 k-rows x 512 cols; 2 KB contiguous reads; LDS transpose (pad 516).
//   bimg frag(nb,kt,kk,nj) at (((nb*64+kt)*4 + kk*2+nj)<<10) + lane*16 holds
//   col o = nb*32+nj*16+(lane&15), k = kt*64+kk*32+(lane>>4)*8+j.
// ---------------------------------------------------------------------------
__global__ __launch_bounds__(256) void snn_conv(
    const float* __restrict__ synw, char* __restrict__ bimg)
{
  __shared__ float ldsf[16 * 516];   // 33 KB
  const int tid = threadIdx.x;
  const int colg = blockIdx.x >> 8;        // 0..7   (512-col group)
  const int kt16 = blockIdx.x & 255;       // 0..255 (16-row group)

  {
    const int row = tid >> 4, c0 = (tid & 15) * 4;
    const float* src = synw + ((size_t)(kt16 * 16 + row)) * N_OUT + colg * 512;
#pragma unroll
    for (int i = 0; i < 8; ++i) {
      float4 v = *(const float4*)(src + c0 + i * 64);
      *(float4*)(&ldsf[row * 516 + c0 + i * 64]) = v;
    }
  }
  __syncthreads();

  const int nb_l = tid >> 4, l15 = tid & 15;
  const int nb = colg * 16 + nb_l;
  const int kt = kt16 >> 2, kk = (kt16 >> 1) & 1, l4b = (kt16 & 1) * 2;
  char* dst0 = bimg + (((size_t)(nb * 64 + kt) * 4 + kk * 2) << 10);
#pragma unroll
  for (int nj = 0; nj < 2; ++nj) {
    const int col = nb_l * 32 + nj * 16 + l15;
#pragma unroll
    for (int h = 0; h < 2; ++h) {
      u32 w0 = f2bf(ldsf[(h * 8 + 0) * 516 + col]) | (f2bf(ldsf[(h * 8 + 1) * 516 + col]) << 16);
      u32 w1 = f2bf(ldsf[(h * 8 + 2) * 516 + col]) | (f2bf(ldsf[(h * 8 + 3) * 516 + col]) << 16);
      u32 w2 = f2bf(ldsf[(h * 8 + 4) * 516 + col]) | (f2bf(ldsf[(h * 8 + 5) * 516 + col]) << 16);
      u32 w3 = f2bf(ldsf[(h * 8 + 6) * 516 + col]) | (f2bf(ldsf[(h * 8 + 7) * 516 + col]) << 16);
      uint4 v; v.x = w0; v.y = w1; v.z = w2; v.w = w3;
      *(uint4*)(dst0 + ((size_t)nj << 10) + ((l4b + h) * 16 + l15) * 16) = v;
    }
  }
}

// ---------------------------------------------------------------------------
// Kernel B: bf16 MFMA GEMM, BM=256 (B-image read once), BN=32, split-K=4.
// Both operands stream through global_load_lds (1 KB/instr, ZERO landing
// VGPRs), ring-2 LDS, counted vmcnt(9) per tile (t+1/t+2 stay in flight),
// raw s_barrier pair per tile (m97 pattern). Epilogue atomically adds the
// fict contribution into out[FICT] (kc==0 folds in memf*decay) -- no part
// buffer, no reduce kernel.
// ---------------------------------------------------------------------------
__global__ __launch_bounds__(256) void snn_gemm(
    const char* __restrict__ aimg, const char* __restrict__ bimg,
    const float* __restrict__ memf, const float* __restrict__ tau,
    const float* __restrict__ dtf_ws, float* __restrict__ out)
{
  __shared__ __align__(16) char ldsA[2][32768];   // [buf][wave 8KB x 4]
  __shared__ __align__(16) char ldsB[2][4096];

  const int tid = threadIdx.x;
  const int lane = tid & 63, wid = tid >> 6;
  const int l15 = lane & 15, l4 = lane >> 4;

  // XCD swizzle: kc pinned per XCD-pair => 512 KB A kc-slice L2-resident
  const int bid = blockIdx.x;
  const int xcd = bid & 7, loc = bid >> 3;       // grid 512: loc 0..63
  const int kc = xcd >> 1;
  const int nb = (xcd & 1) * 64 + loc;           // 0..127
  const int bnb = nb * 32;

  // A: wave w rows w*64..w*64+63 = rg {2w,2w+1}; 8 chunks/tile
  const char* agbase = aimg + (((size_t)(2 * wid * 64 + kc * 16) * 4) << 10) + lane * 16;
  // B: 4 chunks/tile, wave w issues chunk w
  const char* bgbase = bimg + (((size_t)(nb * 64 + kc * 16) * 4 + wid) << 10) + lane * 16;

  auto issueT = [&](int t, int buf) {
    char* ab = &ldsA[buf][wid * 8192];
    const char* ag = agbase + (size_t)t * 4096;
#pragma unroll
    for (int c = 0; c < 4; ++c)                       // rg = 2w
      gload16(ag + c * 1024, ab + c * 1024);
#pragma unroll
    for (int c = 0; c < 4; ++c)                       // rg = 2w+1 (+64 kt-rows)
      gload16(ag + 262144 + c * 1024, ab + 4096 + c * 1024);
    gload16(bgbase + (size_t)t * 4096, &ldsB[buf][wid * 1024]);
  };

  f32x4 acc[4][2] = {};

  auto compute = [&](int buf) {
#pragma unroll
    for (int kk = 0; kk < 2; ++kk)
#pragma unroll
      for (int MI = 0; MI < 4; ++MI) {
        short8 a = *(const short8*)(&ldsA[buf][wid * 8192 + (MI >> 1) * 4096 +
                                               (kk * 2 + (MI & 1)) * 1024 + lane * 16]);
#pragma unroll
        for (int nj = 0; nj < 2; ++nj) {
          short8 b = *(const short8*)(&ldsB[buf][(kk * 2 + nj) * 1024 + lane * 16]);
          acc[MI][nj] = __builtin_amdgcn_mfma_f32_16x16x32_bf16(a, b, acc[MI][nj], 0, 0, 0);
        }
      }
  };

  issueT(0, 0);
  issueT(1, 1);

  // per tile: own vmcnt(9) -> barrier (all waves' tile-t chunks landed) ->
  // ds_read+MFMA -> barrier (all done reading buf) -> issue t+2 into buf.
#define GBODY(T, WAITSTR)                                 \
  {                                                       \
    asm volatile(WAITSTR ::: "memory");                   \
    __builtin_amdgcn_sched_barrier(0);                    \
    __builtin_amdgcn_s_barrier();                         \
    __builtin_amdgcn_sched_barrier(0);                    \
    compute((T) & 1);                                     \
    __builtin_amdgcn_sched_barrier(0);                    \
    __builtin_amdgcn_s_barrier();                         \
    __builtin_amdgcn_sched_barrier(0);                    \
    if ((T) + 2 < 16) issueT((T) + 2, (T) & 1);           \
  }

  for (int t = 0; t < 14; ++t) GBODY(t, "s_waitcnt vmcnt(9)");
  GBODY(14, "s_waitcnt vmcnt(0)");
  GBODY(15, "s_waitcnt vmcnt(0)");
#undef GBODY

  // epilogue: atomic fict accumulation (+ decay term from the kc==0 block)
  float* fict = out + OUT_FICT;
  const bool k0 = (kc == 0);
#pragma unroll
  for (int MI = 0; MI < 4; ++MI)
#pragma unroll
    for (int nj = 0; nj < 2; ++nj) {
      const int o = bnb + nj * 16 + l15;
#pragma unroll
      for (int r = 0; r < 4; ++r) {
        const int b = wid * 64 + MI * 16 + l4 * 4 + r;
        float v = acc[MI][nj][r];
        if (k0) v += memf[(size_t)b * N_OUT + o] * __expf(-tau[o] * dtf_ws[b]);
        atomicAdd(&fict[(size_t)b * N_OUT + o], v);
      }
    }
}

// ---------------------------------------------------------------------------
// Kernel E: phys/act epilogue (independent of weights_sum) + LUT histogram
// (blocks < 256 additionally handle one o-group of 16 columns).
// ---------------------------------------------------------------------------
__global__ __launch_bounds__(256) void snn_epilut(
    const int* __restrict__ memp, const int* __restrict__ dxa_ws,
    const float* __restrict__ mem_map, const float* __restrict__ vth,
    const float* __restrict__ lut_in, float* __restrict__ out)
{
  const int tid = threadIdx.x;
  {
    const int flat = (blockIdx.x * 256 + tid) * 4;
    const int b = flat >> 12, o = flat & 4095;
    const int dxa = dxa_ws[b];
    const int4 mp = *(const int4*)(memp + flat);
    const float4 vv = *(const float4*)(vth + o);
    float4 act, phys;
#define DO(c, oi) { int mpn = (mp.c ^ dxa) & 15; phys.c = (float)mpn; \
                    act.c = (mem_map[(o + oi) * 16 + mpn] >= vv.c) ? 1.f : 0.f; }
    DO(x, 0) DO(y, 1) DO(z, 2) DO(w, 3)
#undef DO
    *(float4*)(out + OUT_ACT  + flat) = act;
    *(float4*)(out + OUT_PHYS + flat) = phys;
  }

  if (blockIdx.x < 256) {
    __shared__ int mp_s[NBAT * 16];
    __shared__ int dxs[NBAT];
    const int o0 = blockIdx.x * 16;
#pragma unroll
    for (int i = 0; i < 16; ++i) {
      int b = i * 16 + (tid >> 4);
      int oj = tid & 15;
      mp_s[b * 16 + oj] = memp[(size_t)b * N_OUT + o0 + oj];
    }
    dxs[tid] = dxa_ws[tid];
    __syncthreads();
    const int o_l = tid >> 4, m = tid & 15;
    int cnt = 0;
#pragma unroll 8
    for (int b = 0; b < NBAT; ++b) {
      int v = (mp_s[b * 16 + o_l] ^ dxs[b]) & 15;
      cnt += (v == m);
    }
    const int o = o0 + o_l;
    const float vmap = mem_map[o * 16 + m];
    out[OUT_LUT + o * 16 + m] = lut_in[o * 16 + m] + 0.5f * ((float)m - vmap) * (float)cnt;
  }
}

// ---------------------------------------------------------------------------
extern "C" void kernel_launch(void* const* d_in, const int* in_sizes, int n_in,
                              void* d_out, int out_size, void* d_ws, size_t ws_size,
                              hipStream_t stream)
{
  const int*   mask    = (const int*)d_in[0];
  const int*   t_ptr   = (const int*)d_in[1];
  const int*   pid     = (const int*)d_in[2];
  const int*   t_last  = (const int*)d_in[3];
  const float* memf    = (const float*)d_in[4];
  const int*   memp    = (const int*)d_in[5];
  const float* lut_in  = (const float*)d_in[6];
  const float* tau     = (const float*)d_in[7];
  const float* vth     = (const float*)d_in[8];
  const float* synw    = (const float*)d_in[9];
  const float* mem_map = (const float*)d_in[10];
  float* out = (float*)d_out;

  char* wsb = (char*)d_ws;
  char*  aimg   = wsb + WS_AIMG;
  char*  bimg   = wsb + WS_BIMG;
  float* dtf_ws = (float*)(wsb + WS_DTF);
  int*   dxa_ws = (int*)(wsb + WS_DXA);

  // zero the fict accumulator region (graph-capture-safe async memset)
  hipMemsetAsync(out + OUT_FICT, 0, (size_t)NBAT * N_OUT * sizeof(float), stream);

  snn_pre<<<NBAT, 256, 0, stream>>>(mask, t_ptr, pid, t_last, dtf_ws, dxa_ws, aimg, out);
  snn_conv<<<2048, 256, 0, stream>>>(synw, bimg);
  snn_gemm<<<512, 256, 0, stream>>>(aimg, bimg, memf, tau, dtf_ws, out);
  snn_epilut<<<(NBAT * N_OUT) / 1024, 256, 0, stream>>>(
      memp, dxa_ws, mem_map, vth, lut_in, out);
}

// Round 12
// 56.462 us; speedup vs baseline: 1.3847x; 1.3847x over previous
//
#include <hip/hip_runtime.h>

typedef __attribute__((ext_vector_type(8))) short short8;
typedef __attribute__((ext_vector_type(4))) float f32x4;
typedef unsigned int u32;
typedef unsigned short u16;

#define N_IN  4096
#define N_OUT 4096
#define NBAT  256

#define OUT_ACT   0
#define OUT_FICT  1048576
#define OUT_PHYS  2097152
#define OUT_LUT   3145728
#define OUT_TLAST 3211264

// ws layout (~51 MB)
#define WS_BITS   0                        // 128 KB bit-packed mask (lane-ordered)
#define WS_BIMG   1048576                  // 32 MB bf16 synw fragment image
#define WS_PART   (WS_BIMG + 33554432)     // 16 MB fp32 partials [4][256][4096]
#define WS_DTF    (WS_PART + 16777216)
#define WS_DXA    (WS_DTF + 1024)

#define SPLITK 4
#define KCHUNK 1024
#define NTK 16            // K-tiles (BK=64) per block

__device__ __forceinline__ unsigned f2bf(float f) {
  unsigned u = __float_as_uint(f);
  return (u + 0x7FFFu + ((u >> 16) & 1u)) >> 16;   // RNE to bf16
}

__device__ __forceinline__ void gload16(const void* g, void* l) {
  __builtin_amdgcn_global_load_lds(
      (const __attribute__((address_space(1))) u32*)g,
      (__attribute__((address_space(3))) u32*)l, 16, 0, 0);
}

// bit-octet -> bf16x8 fragment word (0.0 / 1.0)
__device__ __forceinline__ uint4 expand8(u32 bb) {
  uint4 r;
  r.x = ((bb & 1u)   ? 0x3F80u : 0u) | ((bb & 2u)   ? 0x3F800000u : 0u);
  r.y = ((bb & 4u)   ? 0x3F80u : 0u) | ((bb & 8u)   ? 0x3F800000u : 0u);
  r.z = ((bb & 16u)  ? 0x3F80u : 0u) | ((bb & 32u)  ? 0x3F800000u : 0u);
  r.w = ((bb & 64u)  ? 0x3F80u : 0u) | ((bb & 128u) ? 0x3F800000u : 0u);
  return r;
}

// ---------------------------------------------------------------------------
// Kernel A: prepass. One block per batch row b. Each thread covers 16 mask
// elements (kc,t,l4 mapping), computes the XOR-parity contribution AND packs
// the 16 bits into the lane-ordered bit image:
//   bits_u16[ ((rg*4+kc)*64 + lane)*32 + mi*16 + t ],  rg=b>>5, mi=(b>>4)&1,
//   lane=l4*16+(b&15); bit kk*8+j = mask[b][kc*1024+t*64+kk*32+l4*8+j].
// This is exactly the MFMA A-fragment layout consumed bit->bf16 in the GEMM.
// ---------------------------------------------------------------------------
__global__ __launch_bounds__(256) void snn_pre(
    const int* __restrict__ mask, const int* __restrict__ t_ptr,
    const int* __restrict__ pid, const int* __restrict__ t_last,
    float* __restrict__ dtf_ws, int* __restrict__ dxa_ws,
    u16* __restrict__ bits, float* __restrict__ out)
{
  const int b = blockIdx.x, tid = threadIdx.x;
  const int kc = tid >> 6, t = (tid >> 2) & 15, l4 = tid & 3;
  const int kbase = kc * 1024 + t * 64 + l4 * 8;
  const int* mrow = mask + (size_t)b * N_IN;

  int4 m0 = *(const int4*)(mrow + kbase);
  int4 m1 = *(const int4*)(mrow + kbase + 4);
  int4 m2 = *(const int4*)(mrow + kbase + 32);
  int4 m3 = *(const int4*)(mrow + kbase + 36);
  int4 p0 = *(const int4*)(pid + kbase);
  int4 p1 = *(const int4*)(pid + kbase + 4);
  int4 p2 = *(const int4*)(pid + kbase + 32);
  int4 p3 = *(const int4*)(pid + kbase + 36);

  int x = (m0.x ? p0.x : 0) ^ (m0.y ? p0.y : 0) ^ (m0.z ? p0.z : 0) ^ (m0.w ? p0.w : 0)
        ^ (m1.x ? p1.x : 0) ^ (m1.y ? p1.y : 0) ^ (m1.z ? p1.z : 0) ^ (m1.w ? p1.w : 0)
        ^ (m2.x ? p2.x : 0) ^ (m2.y ? p2.y : 0) ^ (m2.z ? p2.z : 0) ^ (m2.w ? p2.w : 0)
        ^ (m3.x ? p3.x : 0) ^ (m3.y ? p3.y : 0) ^ (m3.z ? p3.z : 0) ^ (m3.w ? p3.w : 0);

  u32 bb = (u32)(m0.x & 1)        | ((u32)(m0.y & 1) << 1)  |
           ((u32)(m0.z & 1) << 2) | ((u32)(m0.w & 1) << 3)  |
           ((u32)(m1.x & 1) << 4) | ((u32)(m1.y & 1) << 5)  |
           ((u32)(m1.z & 1) << 6) | ((u32)(m1.w & 1) << 7)  |
           ((u32)(m2.x & 1) << 8) | ((u32)(m2.y & 1) << 9)  |
           ((u32)(m2.z & 1) << 10)| ((u32)(m2.w & 1) << 11) |
           ((u32)(m3.x & 1) << 12)| ((u32)(m3.y & 1) << 13) |
           ((u32)(m3.z & 1) << 14)| ((u32)(m3.w & 1) << 15);

  {
    const int rg = b >> 5, mi = (b >> 4) & 1, l15 = b & 15;
    const int lane = l4 * 16 + l15;
    bits[((rg * 4 + kc) * 64 + lane) * 32 + mi * 16 + t] = (u16)bb;
  }

  x ^= __shfl_xor(x, 32); x ^= __shfl_xor(x, 16); x ^= __shfl_xor(x, 8);
  x ^= __shfl_xor(x, 4);  x ^= __shfl_xor(x, 2);  x ^= __shfl_xor(x, 1);
  __shared__ int wx[4];
  if ((tid & 63) == 0) wx[tid >> 6] = x;
  __syncthreads();
  if (tid == 0) {
    int acc = wx[0] ^ wx[1] ^ wx[2] ^ wx[3];
    int tt = t_ptr[0];
    int dt = (tt - t_last[b]) & 15;
    dtf_ws[b] = (float)dt;
    dxa_ws[b] = dt ^ (acc & 15);
    out[OUT_TLAST + b] = (float)tt;
  }
}

// ---------------------------------------------------------------------------
// Kernel W: convert synw (fp32 [k][o]) -> bf16 B-fragment image (proven R8).
//   bimg frag(nb,kt,kk,nj) at (((nb*64+kt)*4 + kk*2+nj)<<10) + lane*16 holds
//   col o = nb*32+nj*16+(lane&15), k = kt*64+kk*32+(lane>>4)*8+j.
// ---------------------------------------------------------------------------
__global__ __launch_bounds__(256) void snn_conv(
    const float* __restrict__ synw, char* __restrict__ bimg)
{
  __shared__ float ldsf[16 * 516];   // 33 KB
  const int tid = threadIdx.x;
  const int colg = blockIdx.x >> 8;        // 0..7   (512-col group)
  const int kt16 = blockIdx.x & 255;       // 0..255 (16-row group)

  {
    const int row = tid >> 4, c0 = (tid & 15) * 4;
    const float* src = synw + ((size_t)(kt16 * 16 + row)) * N_OUT + colg * 512;
#pragma unroll
    for (int i = 0; i < 8; ++i) {
      float4 v = *(const float4*)(src + c0 + i * 64);
      *(float4*)(&ldsf[row * 516 + c0 + i * 64]) = v;
    }
  }
  __syncthreads();

  const int nb_l = tid >> 4, l15 = tid & 15;
  const int nb = colg * 16 + nb_l;
  const int kt = kt16 >> 2, kk = (kt16 >> 1) & 1, l4b = (kt16 & 1) * 2;
  char* dst0 = bimg + (((size_t)(nb * 64 + kt) * 4 + kk * 2) << 10);
#pragma unroll
  for (int nj = 0; nj < 2; ++nj) {
    const int col = nb_l * 32 + nj * 16 + l15;
#pragma unroll
    for (int h = 0; h < 2; ++h) {
      u32 w0 = f2bf(ldsf[(h * 8 + 0) * 516 + col]) | (f2bf(ldsf[(h * 8 + 1) * 516 + col]) << 16);
      u32 w1 = f2bf(ldsf[(h * 8 + 2) * 516 + col]) | (f2bf(ldsf[(h * 8 + 3) * 516 + col]) << 16);
      u32 w2 = f2bf(ldsf[(h * 8 + 4) * 516 + col]) | (f2bf(ldsf[(h * 8 + 5) * 516 + col]) << 16);
      u32 w3 = f2bf(ldsf[(h * 8 + 6) * 516 + col]) | (f2bf(ldsf[(h * 8 + 7) * 516 + col]) << 16);
      uint4 v; v.x = w0; v.y = w1; v.z = w2; v.w = w3;
      *(uint4*)(dst0 + ((size_t)nj << 10) + ((l4b + h) * 16 + l15) * 16) = v;
    }
  }
}

// component / u16 extraction helpers (all compile-time folded in unrolled loop)
#define COMPI(V, I) ((I) == 0 ? (V).x : (I) == 1 ? (V).y : (I) == 2 ? (V).z : (V).w)
#define U16X(W0, W1, T) \
  (((((T) < 8) ? COMPI(W0, ((T) & 7) >> 1) : COMPI(W1, ((T) & 7) >> 1)) >> (((T) & 1) * 16)) & 0xFFFFu)

// ---------------------------------------------------------------------------
// Kernel B: bf16 MFMA GEMM, split-K=4, BM=128, BN=32, grid 1024 (4 blk/CU).
// A operand = IN-REGISTER BITS (16 VGPR/thread, loaded once) expanded to
// bf16 fragments on the fly -- zero A staging traffic/latency in the loop.
// B = 4 KB/step contiguous stream from bimg via global_load_lds, ring-3 LDS,
// counted vmcnt(2) (2 tiles always in flight). LDS total 12 KB.
// ---------------------------------------------------------------------------
__global__ __launch_bounds__(256) void snn_gemm(
    const u16* __restrict__ bits, const char* __restrict__ bimg,
    float* __restrict__ part)
{
  __shared__ __align__(16) char ldsB[3][4096];

  const int tid = threadIdx.x;
  const int lane = tid & 63, wid = tid >> 6;
  const int l15 = lane & 15, l4 = lane >> 4;

  const int bid = blockIdx.x;
  const int xcd = bid & 7, loc = bid >> 3;   // grid 1024: loc 0..127
  const int kc = xcd >> 1;                   // XCD pair shares kc
  const int mb = xcd & 1;
  const int nb = loc;                        // block streams contiguous 64 KB of bimg
  const int rg = mb * 4 + wid;

  // A bits: 64 B per thread, the ENTIRE A operand for this block's K-chunk
  const uint4* bp = (const uint4*)(bits + (((rg * 4 + kc) * 64 + lane) << 5));
  const uint4 w0 = bp[0], w1 = bp[1];   // mi=0, t=0..15
  const uint4 w2 = bp[2], w3 = bp[3];   // mi=1, t=0..15

  const char* bgbase = bimg + ((size_t)(nb * 64 + kc * 16) << 12) + wid * 1024 + lane * 16;

  f32x4 acc00 = {}, acc01 = {}, acc10 = {}, acc11 = {};

  // prologue: tiles 0,1 in flight
  gload16(bgbase,        &ldsB[0][wid * 1024]);
  gload16(bgbase + 4096, &ldsB[1][wid * 1024]);

#define STEP(T)                                                              \
  {                                                                          \
    gload16(bgbase + (size_t)(((T) + 2) & 15) * 4096,                        \
            &ldsB[((T) + 2) % 3][wid * 1024]);                               \
    asm volatile("s_waitcnt vmcnt(2)" ::: "memory");                         \
    __builtin_amdgcn_sched_barrier(0);                                       \
    __builtin_amdgcn_s_barrier();                                            \
    __builtin_amdgcn_sched_barrier(0);                                       \
    const char* bl = ldsB[(T) % 3];                                          \
    short8 b00 = *(const short8*)(bl + 0 * 1024 + lane * 16);                \
    short8 b01 = *(const short8*)(bl + 1 * 1024 + lane * 16);                \
    short8 b10 = *(const short8*)(bl + 2 * 1024 + lane * 16);                \
    short8 b11 = *(const short8*)(bl + 3 * 1024 + lane * 16);                \
    const u32 m0t = U16X(w0, w1, T);                                         \
    const u32 m1t = U16X(w2, w3, T);                                         \
    uint4 a00 = expand8(m0t & 0xFFu);                                        \
    uint4 a01 = expand8(m0t >> 8);                                           \
    uint4 a10 = expand8(m1t & 0xFFu);                                        \
    uint4 a11 = expand8(m1t >> 8);                                           \
    acc00 = __builtin_amdgcn_mfma_f32_16x16x32_bf16(*(const short8*)&a00, b00, acc00, 0, 0, 0); \
    acc01 = __builtin_amdgcn_mfma_f32_16x16x32_bf16(*(const short8*)&a00, b01, acc01, 0, 0, 0); \
    acc10 = __builtin_amdgcn_mfma_f32_16x16x32_bf16(*(const short8*)&a10, b00, acc10, 0, 0, 0); \
    acc11 = __builtin_amdgcn_mfma_f32_16x16x32_bf16(*(const short8*)&a10, b01, acc11, 0, 0, 0); \
    acc00 = __builtin_amdgcn_mfma_f32_16x16x32_bf16(*(const short8*)&a01, b10, acc00, 0, 0, 0); \
    acc01 = __builtin_amdgcn_mfma_f32_16x16x32_bf16(*(const short8*)&a01, b11, acc01, 0, 0, 0); \
    acc10 = __builtin_amdgcn_mfma_f32_16x16x32_bf16(*(const short8*)&a11, b10, acc10, 0, 0, 0); \
    acc11 = __builtin_amdgcn_mfma_f32_16x16x32_bf16(*(const short8*)&a11, b11, acc11, 0, 0, 0); \
    __builtin_amdgcn_s_barrier();                                            \
  }

  STEP(0)  STEP(1)  STEP(2)  STEP(3)
  STEP(4)  STEP(5)  STEP(6)  STEP(7)
  STEP(8)  STEP(9)  STEP(10) STEP(11)
  STEP(12) STEP(13) STEP(14) STEP(15)
#undef STEP

  float* pb = part + (size_t)kc * (NBAT * N_OUT);
  {
    const int o0 = nb * 32 + l15, o1 = o0 + 16;
    const int br = mb * 128 + wid * 32 + l4 * 4;
#pragma unroll
    for (int r = 0; r < 4; ++r) {
      pb[(size_t)(br + r) * N_OUT + o0]      = acc00[r];
      pb[(size_t)(br + r) * N_OUT + o1]      = acc01[r];
      pb[(size_t)(br + 16 + r) * N_OUT + o0] = acc10[r];
      pb[(size_t)(br + 16 + r) * N_OUT + o1] = acc11[r];
    }
  }
}

// ---------------------------------------------------------------------------
// Kernel C: split-K reduce + fused epilogue (decay, phys, act) + LUT
// histogram (blocks < 256 each own one o-group of 16 columns).
// ---------------------------------------------------------------------------
__global__ __launch_bounds__(256) void snn_reduce(
    const float* __restrict__ part, const float* __restrict__ memf,
    const int* __restrict__ memp, const float* __restrict__ tau,
    const float* __restrict__ vth, const float* __restrict__ mem_map,
    const float* __restrict__ dtf_ws, const int* __restrict__ dxa_ws,
    const float* __restrict__ lut_in, float* __restrict__ out)
{
  const int tid = threadIdx.x;
  {
    const int flat = (blockIdx.x * 256 + tid) * 4;
    const int b = flat >> 12, o = flat & 4095;
    const float4 p0 = *(const float4*)(part + flat);
    const float4 p1 = *(const float4*)(part + 1048576 + flat);
    const float4 p2 = *(const float4*)(part + 2097152 + flat);
    const float4 p3 = *(const float4*)(part + 3145728 + flat);
    float4 ws;
    ws.x = (p0.x + p1.x) + (p2.x + p3.x);
    ws.y = (p0.y + p1.y) + (p2.y + p3.y);
    ws.z = (p0.z + p1.z) + (p2.z + p3.z);
    ws.w = (p0.w + p1.w) + (p2.w + p3.w);
    const float dtf = dtf_ws[b];
    const int dxa = dxa_ws[b];
    const float4 mf = *(const float4*)(memf + flat);
    const int4  mp = *(const int4*)(memp + flat);
    const float4 tv = *(const float4*)(tau + o);
    const float4 vv = *(const float4*)(vth + o);
    float4 act, fict, phys;
#define DO(c, oi) { float d = __expf(-tv.c * dtf); fict.c = mf.c * d + ws.c; \
                    int mpn = (mp.c ^ dxa) & 15; phys.c = (float)mpn; \
                    act.c = (mem_map[(o + oi) * 16 + mpn] >= vv.c) ? 1.f : 0.f; }
    DO(x, 0) DO(y, 1) DO(z, 2) DO(w, 3)
#undef DO
    *(float4*)(out + OUT_ACT  + flat) = act;
    *(float4*)(out + OUT_FICT + flat) = fict;
    *(float4*)(out + OUT_PHYS + flat) = phys;
  }

  if (blockIdx.x < 256) {
    __shared__ int mp_s[NBAT * 16];
    __shared__ int dxs[NBAT];
    const int o0 = blockIdx.x * 16;
#pragma unroll
    for (int i = 0; i < 16; ++i) {
      int b = i * 16 + (tid >> 4);
      int oj = tid & 15;
      mp_s[b * 16 + oj] = memp[(size_t)b * N_OUT + o0 + oj];
    }
    dxs[tid] = dxa_ws[tid];
    __syncthreads();
    const int o_l = tid >> 4, m = tid & 15;
    int cnt = 0;
#pragma unroll 8
    for (int b = 0; b < NBAT; ++b) {
      int v = (mp_s[b * 16 + o_l] ^ dxs[b]) & 15;
      cnt += (v == m);
    }
    const int o = o0 + o_l;
    const float vmap = mem_map[o * 16 + m];
    out[OUT_LUT + o * 16 + m] = lut_in[o * 16 + m] + 0.5f * ((float)m - vmap) * (float)cnt;
  }
}

// ---------------------------------------------------------------------------
extern "C" void kernel_launch(void* const* d_in, const int* in_sizes, int n_in,
                              void* d_out, int out_size, void* d_ws, size_t ws_size,
                              hipStream_t stream)
{
  const int*   mask    = (const int*)d_in[0];
  const int*   t_ptr   = (const int*)d_in[1];
  const int*   pid     = (const int*)d_in[2];
  const int*   t_last  = (const int*)d_in[3];
  const float* memf    = (const float*)d_in[4];
  const int*   memp    = (const int*)d_in[5];
  const float* lut_in  = (const float*)d_in[6];
  const float* tau     = (const float*)d_in[7];
  const float* vth     = (const float*)d_in[8];
  const float* synw    = (const float*)d_in[9];
  const float* mem_map = (const float*)d_in[10];
  float* out = (float*)d_out;

  char* wsb = (char*)d_ws;
  u16*   bits   = (u16*)(wsb + WS_BITS);
  char*  bimg   = wsb + WS_BIMG;
  float* part   = (float*)(wsb + WS_PART);
  float* dtf_ws = (float*)(wsb + WS_DTF);
  int*   dxa_ws = (int*)(wsb + WS_DXA);

  snn_pre<<<NBAT, 256, 0, stream>>>(mask, t_ptr, pid, t_last, dtf_ws, dxa_ws, bits, out);
  snn_conv<<<2048, 256, 0, stream>>>(synw, bimg);
  snn_gemm<<<1024, 256, 0, stream>>>(bits, bimg, part);
  snn_reduce<<<(NBAT * N_OUT) / 1024, 256, 0, stream>>>(
      part, memf, memp, tau, vth, mem_map, dtf_ws, dxa_ws, lut_in, out);
}